// Round 4
// baseline (435.204 us; speedup 1.0000x reference)
//
#include <hip/hip_runtime.h>
#include <math.h>

// Problem constants
#define B 32
#define N 4096
#define D 128
#define KTOP 512
#define NPB 2048
#define MSEG (B * NPB)      // 65536
#define E (B * N)           // 131072
#define K7ROWS 16           // rows per k7 block

// ---------------------------------------------------------------------------
// K0: per-batch precompute (fp64): query = cat(qh,qr,qt)@W_q+b_q,
// u_d = q_d*W1_d - W2_d + W3_d, v = W_a @ u, c2 = q.(W2+W3)+b_att+b_a.u
// (zeroing removed: k2_agg owns all per-segment state in LDS now).
// ---------------------------------------------------------------------------
__global__ __launch_bounds__(384) void k0_precompute(
    const float* __restrict__ qh, const float* __restrict__ qr,
    const float* __restrict__ qt, const float* __restrict__ Wq,
    const float* __restrict__ bq, const float* __restrict__ Wa,
    const float* __restrict__ ba, const float* __restrict__ Watt,
    const float* __restrict__ batt, float* __restrict__ vf,
    float* __restrict__ c2f) {
  int b = blockIdx.x;
  int tid = threadIdx.x;
  int d = tid & 127;
  int g = tid >> 7;  // 0..2, wave-uniform (384 = 6 waves)
  __shared__ double part[3][128];
  __shared__ double u[128];
  __shared__ double red[128];
  const float* xs = (g == 0 ? qh : (g == 1 ? qr : qt)) + b * 128;
  const float* Wg = Wq + g * 128 * 128;
  double a0 = 0, a1 = 0, a2 = 0, a3 = 0;
#pragma unroll 4
  for (int i = 0; i < 128; i += 4) {
    a0 += (double)xs[i] * (double)Wg[i * 128 + d];
    a1 += (double)xs[i + 1] * (double)Wg[(i + 1) * 128 + d];
    a2 += (double)xs[i + 2] * (double)Wg[(i + 2) * 128 + d];
    a3 += (double)xs[i + 3] * (double)Wg[(i + 3) * 128 + d];
  }
  part[g][d] = (a0 + a1) + (a2 + a3);
  __syncthreads();
  if (g == 0) {
    double acc = (double)bq[d] + part[0][d] + part[1][d] + part[2][d];
    double w1 = (double)Watt[d], w2 = (double)Watt[128 + d],
           w3 = (double)Watt[256 + d];
    double ud = acc * w1 - w2 + w3;
    u[d] = ud;
    red[d] = acc * (w2 + w3) + (double)ba[d] * ud;
  }
  __syncthreads();
  for (int s = 64; s > 0; s >>= 1) {
    if (tid < s) red[tid] += red[tid + s];
    __syncthreads();
  }
  if (tid == 0) c2f[b] = (float)(red[0] + (double)batt[0]);
  // phase B: one W_a row per thread (384 rows, 384 threads)
  {
    double v0 = 0, v1 = 0, v2 = 0, v3 = 0;
    const float* Wr = Wa + tid * 128;
#pragma unroll 4
    for (int dd = 0; dd < 128; dd += 4) {
      v0 += (double)Wr[dd] * u[dd];
      v1 += (double)Wr[dd + 1] * u[dd + 1];
      v2 += (double)Wr[dd + 2] * u[dd + 2];
      v3 += (double)Wr[dd + 3] * u[dd + 3];
    }
    vf[b * 384 + tid] = (float)((v0 + v1) + (v2 + v3));
  }
}

// ---------------------------------------------------------------------------
// K1: per-edge attention, fp32, PURE STREAMING: 4 coalesced input streams,
// butterfly reduce, one attw store per edge. No tidx loads, no atomics, no
// lists (R3 showed atomic write-through was a ~14MB/+7us tax; all per-segment
// work moved to k2_agg's LDS). 32 lanes per edge, float4 per lane, depth-2
// pipeline at <=64 VGPR / high occupancy (k1 proven scheduling-invariant
// R0-R3, so simplest high-occupancy shape).
// ---------------------------------------------------------------------------
__global__ __launch_bounds__(256, 8) void k1_att(
    const float* __restrict__ r, const float* __restrict__ t,
    const float* __restrict__ tm, const float* __restrict__ hidden,
    const float* __restrict__ Wrule, const float* __restrict__ brule,
    const float* __restrict__ vf, const float* __restrict__ c2f,
    float* __restrict__ attw) {
  int tid = threadIdx.x;
  int h = tid >> 5;       // half-wave id 0..7
  int l = tid & 31;       // lane within 32
  int base = blockIdx.x * 64;
  int b = base >> 12;     // batch (uniform over block)
  const float4* vb = (const float4*)(vf + b * 384);
  float4 v0 = vb[l];
  float4 v1 = vb[32 + l];
  float4 v2 = vb[64 + l];
  float4 wr = ((const float4*)Wrule)[l];
  float c2 = c2f[b];
  float br = brule[0];
  float mya = 0.f;
  unsigned lo = (unsigned)(l * 4);
  float4 ra[2], ta[2], ma[2], ha[2];
  {
    unsigned eo = ((unsigned)(base + h) << 7) + lo;
    ra[0] = *(const float4*)(r + eo);
    ta[0] = *(const float4*)(t + eo);
    ma[0] = *(const float4*)(tm + eo);
    ha[0] = *(const float4*)(hidden + eo);
  }
#pragma unroll
  for (int i = 0; i < 8; ++i) {
    const int cur = i & 1;
    if (i < 7) {  // prefetch next edge into the other slot
      const int nxt = cur ^ 1;
      unsigned eo = ((unsigned)(base + (i + 1) * 8 + h) << 7) + lo;
      ra[nxt] = *(const float4*)(r + eo);
      ta[nxt] = *(const float4*)(t + eo);
      ma[nxt] = *(const float4*)(tm + eo);
      ha[nxt] = *(const float4*)(hidden + eo);
    }
    float4 A = ra[cur], T = ta[cur], M = ma[cur], H = ha[cur];
    float p1 = A.x * v0.x + A.y * v0.y + A.z * v0.z + A.w * v0.w;
    p1 += T.x * v1.x + T.y * v1.y + T.z * v1.z + T.w * v1.w;
    p1 += M.x * v2.x + M.y * v2.y + M.z * v2.z + M.w * v2.w;
    float p2 = H.x * wr.x + H.y * wr.y + H.z * wr.z + H.w * wr.w;
#pragma unroll
    for (int off = 16; off > 0; off >>= 1) {
      p1 += __shfl_xor(p1, off);
      p2 += __shfl_xor(p2, off);
    }
    // every lane holds the full reduction; lane i latches edge i's result
    if (l == i) {
      float a1 = 1.0f / (1.0f + expf(-(p1 + c2)));
      float a2 = 1.0f / (1.0f + expf(-(p2 + br)));
      mya = 0.5f * (a1 + a2);
    }
  }
  if (l < 8) attw[base + l * 8 + h] = mya;  // lane l holds edge base+l*8+h
}

// ---------------------------------------------------------------------------
// K2_AGG: one block per batch (32 x 512). All per-segment state in LDS:
//  - agg[2048] as u64 fixed-point (att * 2^57): EXACT, order-independent sum;
//    error vs reference fp32 agg ~7e-15, same regime as the fp64 atomics that
//    passed R0-R3.
//  - counts -> prefix sum -> PACKED per-segment edge lists (u16 local ids,
//    offp[m] global offsets; cnt = offp[m+1]-offp[m], telescopes across
//    batches; no MAXC cap anymore).
//  - exact top-K via bucketed rank-count: 512-bucket histogram on agg>>54;
//    candidates whose strictly-higher-bucket count >= K are skipped (rank
//    proof: rank >= above); boundary buckets rank-counted exactly by
//    (value, index) against same-bucket members only (~40/bucket typ).
// Replaces: k6, kb_build, all global atomics, k0's zeroing.
// ---------------------------------------------------------------------------
__global__ __launch_bounds__(512) void k2_agg(
    const float* __restrict__ attw, const int* __restrict__ tidx,
    const int* __restrict__ tail_nodes, unsigned* __restrict__ offp,
    unsigned short* __restrict__ packed, float* __restrict__ out_nodes,
    int* __restrict__ idxw) {
  __shared__ unsigned long long aggu[2048];  // 16 KB
  __shared__ unsigned cnt[2048];             // 8 KB (reused as fill cursor)
  __shared__ unsigned off[2048];             // 8 KB
  __shared__ unsigned partial[512];          // 2 KB
  __shared__ unsigned hist[512];             // 2 KB
  __shared__ unsigned hsuf[513];             // suffix-inclusive counts
  __shared__ unsigned hstart[512];           // forward-exclusive (scatter base)
  __shared__ unsigned bcur[512];             // scatter cursor
  __shared__ unsigned short sorted[2048];    // 4 KB bucket-grouped indices
  int b = blockIdx.x;
  int tid = threadIdx.x;
  for (int i = tid; i < 2048; i += 512) { aggu[i] = 0ull; cnt[i] = 0u; }
  if (tid < 512) hist[tid] = 0u;
  __syncthreads();
  // ---- edge scan: 4096 edges of this batch, 8 per thread, coalesced ----
  int ebase = b * 4096;
  int locseg[8];
  float av[8];
#pragma unroll
  for (int k = 0; k < 8; ++k) {
    int e = ebase + tid + k * 512;
    locseg[k] = tidx[e] & 2047;  // segment local to batch (tidx = b*2048+loc)
    av[k] = attw[e];
  }
#pragma unroll
  for (int k = 0; k < 8; ++k) {
    // att in (0,1): a*2^57 < 2^57; <=4096 terms < 2^69? no: per segment <=~32,
    // practically < 2^62. Exact integer sum, deterministic.
    unsigned long long q =
        (unsigned long long)((double)av[k] * 144115188075855872.0);  // 2^57
    atomicAdd(&aggu[locseg[k]], q);
    atomicAdd(&cnt[locseg[k]], 1u);
  }
  __syncthreads();
  // ---- exclusive prefix sum cnt -> off (4 bins/thread + 512-scan) ----
  {
    unsigned c0 = cnt[tid * 4], c1 = cnt[tid * 4 + 1];
    unsigned c2v = cnt[tid * 4 + 2], c3 = cnt[tid * 4 + 3];
    unsigned s = c0 + c1 + c2v + c3;
    partial[tid] = s;
    __syncthreads();
    for (int st = 1; st < 512; st <<= 1) {
      unsigned x = partial[tid];
      unsigned y = (tid >= st) ? partial[tid - st] : 0u;
      __syncthreads();
      partial[tid] = x + y;
      __syncthreads();
    }
    unsigned basep = partial[tid] - s;  // exclusive
    off[tid * 4] = basep;
    off[tid * 4 + 1] = basep + c0;
    off[tid * 4 + 2] = basep + c0 + c1;
    off[tid * 4 + 3] = basep + c0 + c1 + c2v;
  }
  __syncthreads();
  // ---- global offp (coalesced) + histogram ----
  for (int i = tid; i < 2048; i += 512)
    offp[b * 2048 + i] = (unsigned)(b * 4096) + off[i];
  if (b == B - 1 && tid == 0) offp[MSEG] = E;  // sentinel (telescopes)
  for (int i = tid; i < 2048; i += 512)
    atomicAdd(&hist[(unsigned)(aggu[i] >> 54)], 1u);
  __syncthreads();
  // ---- packed fill: cnt becomes cursor = off ----
  for (int i = tid; i < 2048; i += 512) cnt[i] = off[i];
  __syncthreads();
#pragma unroll
  for (int k = 0; k < 8; ++k) {
    unsigned pos = atomicAdd(&cnt[locseg[k]], 1u);
    packed[b * 4096 + pos] = (unsigned short)(tid + k * 512);  // local edge id
  }
  // ---- scans over hist: forward-exclusive (hstart) + suffix-inclusive ----
  {
    partial[tid] = hist[tid];
    __syncthreads();
    for (int st = 1; st < 512; st <<= 1) {
      unsigned x = partial[tid];
      unsigned y = (tid >= st) ? partial[tid - st] : 0u;
      __syncthreads();
      partial[tid] = x + y;
      __syncthreads();
    }
    unsigned fex = partial[tid] - hist[tid];
    hstart[tid] = fex;
    hsuf[tid] = 2048u - fex;  // sum_{c'>=tid} hist[c']
    if (tid == 0) hsuf[512] = 0u;
    bcur[tid] = fex;
    __syncthreads();
  }
  // ---- scatter indices into bucket-grouped order ----
  for (int i = tid; i < 2048; i += 512) {
    unsigned bkt = (unsigned)(aggu[i] >> 54);
    unsigned p = atomicAdd(&bcur[bkt], 1u);
    sorted[p] = (unsigned short)i;
  }
  __syncthreads();
  // ---- exact rank within boundary buckets; emit top-K ----
  for (int c = 0; c < 4; ++c) {
    int i = c * 512 + tid;
    unsigned long long vi = aggu[i];
    unsigned bkt = (unsigned)(vi >> 54);
    unsigned above = hsuf[bkt + 1];  // strictly higher buckets
    if (above >= KTOP) continue;     // rank >= above >= K: not selected
    unsigned rank = above;
    unsigned s0 = hstart[bkt];
    unsigned s1 = s0 + (hsuf[bkt] - hsuf[bkt + 1]);  // + hist[bkt]
    for (unsigned k = s0; k < s1; ++k) {
      int j = sorted[k];
      unsigned long long vj = aggu[j];
      rank += (vj > vi) || (vj == vi && j < i);
    }
    if (rank < KTOP) {
      int gm = b * 2048 + i;
      int p = b * KTOP + (int)rank;
      out_nodes[p * 2 + 0] = (float)tail_nodes[gm * 3 + 1];
      out_nodes[p * 2 + 1] = (float)tail_nodes[gm * 3 + 2];
      idxw[p] = gm;
    }
  }
}

// ---------------------------------------------------------------------------
// K7: selected rows only, reading PACKED lists (offp/packed, L2-hot).
// Phase 1: batched index rounds (idxw x8 -> offp pairs x8 -> first-4 edge ids
// x8), then PREDICATED unconditional gather (R3's win) -- garbage decodes stay
// in-batch/in-bounds, contributions masked. Tail (cnt>4) branchy, uncapped.
// Phase 2: out_emd = es @ W_out + b_out.
// ---------------------------------------------------------------------------
__global__ __launch_bounds__(256) void k7_out(
    const float* __restrict__ tail_emd, const float* __restrict__ r,
    const float* __restrict__ tm, const float* __restrict__ hidden,
    const float* __restrict__ qh, const float* __restrict__ attw,
    const unsigned* __restrict__ offp, const unsigned short* __restrict__ packed,
    const float* __restrict__ Wout, const float* __restrict__ bout,
    const int* __restrict__ idxw, float* __restrict__ out_emd,
    float* __restrict__ out_hid) {
  __shared__ float es[K7ROWS][128];
  int tid = threadIdx.x;
  int sub = tid >> 7, d = tid & 127;
  int base = blockIdx.x * K7ROWS;
  int mrow[8];
  unsigned o0r[8], cntr[8];
#pragma unroll
  for (int jj = 0; jj < 8; ++jj) mrow[jj] = idxw[base + jj * 2 + sub];
#pragma unroll
  for (int jj = 0; jj < 8; ++jj) {
    unsigned o0 = offp[mrow[jj]];
    unsigned o1 = offp[mrow[jj] + 1];
    o0r[jj] = o0;
    cntr[jj] = o1 - o0;
  }
  unsigned short e4[8][4];
#pragma unroll
  for (int jj = 0; jj < 8; ++jj)
#pragma unroll
    for (int k = 0; k < 4; ++k) e4[jj][k] = packed[o0r[jj] + k];  // padded tail
#pragma unroll
  for (int jj = 0; jj < 8; ++jj) {
    int m = mrow[jj];
    int bb = m >> 11;
    unsigned ebase = (unsigned)bb << 12;
    int cnt = (int)cntr[jj];
    float accT = tail_emd[(size_t)m * 128 + d];
    float accH = 0.f;
    float qhd = qh[bb * 128 + d];
    unsigned e0 = ebase | (e4[jj][0] & 4095u);
    unsigned e1 = ebase | (e4[jj][1] & 4095u);
    unsigned e2 = ebase | (e4[jj][2] & 4095u);
    unsigned e3 = ebase | (e4[jj][3] & 4095u);
    float m0 = cnt > 0 ? 1.f : 0.f;
    float m1 = cnt > 1 ? 1.f : 0.f;
    float m2 = cnt > 2 ? 1.f : 0.f;
    float m3 = cnt > 3 ? 1.f : 0.f;
    float a0 = attw[e0], a1 = attw[e1], a2 = attw[e2], a3 = attw[e3];
    unsigned o0 = (e0 << 7) + d, o1 = (e1 << 7) + d;
    unsigned o2 = (e2 << 7) + d, o3 = (e3 << 7) + d;
    float r0 = r[o0], r1 = r[o1], r2 = r[o2], r3 = r[o3];
    float t0 = tm[o0], t1 = tm[o1], t2 = tm[o2], t3 = tm[o3];
    float h0 = hidden[o0], h1 = hidden[o1], h2 = hidden[o2], h3 = hidden[o3];
    accT += m0 * a0 * (qhd + r0 + t0);
    accT += m1 * a1 * (qhd + r1 + t1);
    accT += m2 * a2 * (qhd + r2 + t2);
    accT += m3 * a3 * (qhd + r3 + t3);
    accH += m0 * h0 + m1 * h1 + m2 * h2 + m3 * h3;
    for (int k = 4; k < cnt; ++k) {  // rare tail, uncapped
      unsigned e = ebase | (packed[o0r[jj] + k] & 4095u);
      float a = attw[e];
      unsigned eo = (e << 7) + d;
      accT += a * (qhd + r[eo] + tm[eo]);
      accH += hidden[eo];
    }
    es[jj * 2 + sub][d] = accT;
    out_hid[(size_t)(base + jj * 2 + sub) * 128 + d] = accH;
  }
  __syncthreads();
  // ---- phase 2: GEMM es(16x128) @ Wout(128x128) ----
  int cg = tid & 31;   // columns cg*4 .. cg*4+3
  int rg = tid >> 5;   // row pair rg*2, rg*2+1
  float4 bo = *(const float4*)(bout + cg * 4);
  float acc0x = bo.x, acc0y = bo.y, acc0z = bo.z, acc0w = bo.w;
  float acc1x = bo.x, acc1y = bo.y, acc1z = bo.z, acc1w = bo.w;
#pragma unroll 4
  for (int i = 0; i < 128; ++i) {
    float4 w = *(const float4*)(Wout + i * 128 + cg * 4);
    float e0 = es[rg * 2 + 0][i];
    float e1 = es[rg * 2 + 1][i];
    acc0x += e0 * w.x; acc0y += e0 * w.y; acc0z += e0 * w.z; acc0w += e0 * w.w;
    acc1x += e1 * w.x; acc1y += e1 * w.y; acc1z += e1 * w.z; acc1w += e1 * w.w;
  }
  size_t r0o = (size_t)(base + rg * 2) * 128 + cg * 4;
  *(float4*)(out_emd + r0o) = make_float4(acc0x, acc0y, acc0z, acc0w);
  *(float4*)(out_emd + r0o + 128) = make_float4(acc1x, acc1y, acc1z, acc1w);
}

// ---------------------------------------------------------------------------
extern "C" void kernel_launch(void* const* d_in, const int* in_sizes, int n_in,
                              void* d_out, int out_size, void* d_ws,
                              size_t ws_size, hipStream_t stream) {
  const float* q_head = (const float*)d_in[0];
  const float* q_rel = (const float*)d_in[1];
  const float* q_time = (const float*)d_in[2];
  const float* r_nb = (const float*)d_in[3];
  const float* t_nb = (const float*)d_in[4];
  const float* tm_nb = (const float*)d_in[5];
  const float* hidden = (const float*)d_in[6];
  const float* tail_emd = (const float*)d_in[7];
  const int* tail_index = (const int*)d_in[8];
  const int* tail_nodes = (const int*)d_in[9];
  const float* W_q = (const float*)d_in[10];
  const float* b_q = (const float*)d_in[11];
  const float* W_a = (const float*)d_in[12];
  const float* b_a = (const float*)d_in[13];
  const float* W_att = (const float*)d_in[14];
  const float* b_att = (const float*)d_in[15];
  const float* W_rule = (const float*)d_in[16];
  const float* b_rule = (const float*)d_in[17];
  const float* W_out = (const float*)d_in[18];
  const float* b_out = (const float*)d_in[19];

  char* ws = (char*)d_ws;
  float* vf = (float*)(ws + 0);               // 32*384*4 = 49152
  float* c2f = (float*)(ws + 49152);          // 128 B -> pad to 49280
  float* attw = (float*)(ws + 49280);         // E*4 = 524288 -> 573568
  unsigned* offp = (unsigned*)(ws + 573568);  // (MSEG+1)*4 = 262148 -> 835776
  unsigned short* packed = (unsigned short*)(ws + 835776);  // (E+8)*2 -> 1097984
  int* idxw = (int*)(ws + 1097984);           // B*K*4 = 65536 -> 1163520

  float* out_nodes = (float*)d_out;                       // B*K*2
  float* out_emd = (float*)d_out + (size_t)B * KTOP * 2;  // B*K*128
  float* out_hid = out_emd + (size_t)B * KTOP * 128;      // B*K*128

  // 4 dispatches: no memsets, no global atomics anywhere.
  k0_precompute<<<B, 384, 0, stream>>>(q_head, q_rel, q_time, W_q, b_q, W_a,
                                       b_a, W_att, b_att, vf, c2f);
  k1_att<<<E / 64, 256, 0, stream>>>(r_nb, t_nb, tm_nb, hidden, W_rule, b_rule,
                                     vf, c2f, attw);
  k2_agg<<<B, 512, 0, stream>>>(attw, tail_index, tail_nodes, offp, packed,
                                out_nodes, idxw);
  k7_out<<<(B * KTOP) / K7ROWS, 256, 0, stream>>>(tail_emd, r_nb, tm_nb,
                                                  hidden, q_head, attw, offp,
                                                  packed, W_out, b_out, idxw,
                                                  out_emd, out_hid);
}